// Round 1
// baseline (16.714 us; speedup 1.0000x reference)
//
#include <hip/hip_runtime.h>
#include <math.h>

// DescriptorMatcher: b=1, c=64, N=1024 voxels per volume.
// out  [N*N, 2]  : out[n1,n2,o] = sum_c v1[n1,c]*v2[n2,c]*W[o,c] + bias[o]
// onorm[N, N]    : || v1/(eps+|v1|) - v2/(eps+|v2|) ||_2
// Decomposition: 3 weighted dot products per pair (w0, w1, ones) + per-row
// norm scalars. Tile 64x64 pairs per block, LDS [c][j] layout (stride 64,
// conflict-free, b128 fragment reads), 256 threads, 4x4 pairs per thread.

#define CDIM 64
#define TILE 64
#define EPSN 1e-6f

typedef float f4 __attribute__((ext_vector_type(4)));

__global__ __launch_bounds__(256, 2)
void descmatch_kernel(const float* __restrict__ g1,
                      const float* __restrict__ g2,
                      const float* __restrict__ W,
                      const float* __restrict__ bias,
                      float* __restrict__ out,
                      float* __restrict__ onorm,
                      int N) {
    __shared__ float v1s[CDIM][TILE];   // [c][i]
    __shared__ float v2s[CDIM][TILE];   // [c][j]
    __shared__ float v2w0[CDIM][TILE];
    __shared__ float v2w1[CDIM][TILE];
    __shared__ float s1t[TILE], r1t[TILE], s2t[TILE], r2t[TILE];

    const int t  = threadIdx.x;
    const int i0 = blockIdx.y * TILE;
    const int j0 = blockIdx.x * TILE;

    // ---- stage tiles: global [c][n] -> LDS [c][tile] (coalesced, no transpose)
    #pragma unroll
    for (int p = 0; p < (CDIM * TILE) / 256; ++p) {
        int idx = p * 256 + t;
        int c = idx >> 6;       // idx / 64
        int j = idx & 63;       // idx % 64
        float a = g1[c * N + i0 + j];
        float b = g2[c * N + j0 + j];
        float w0 = W[c];
        float w1 = W[CDIM + c];
        v1s[c][j]  = a;
        v2s[c][j]  = b;
        v2w0[c][j] = b * w0;
        v2w1[c][j] = b * w1;
    }
    __syncthreads();

    // ---- per-row norm scalars (threads 0..127, one row each)
    if (t < 2 * TILE) {
        int r = t & (TILE - 1);
        float ss = 0.f;
        if (t < TILE) {
            #pragma unroll
            for (int c = 0; c < CDIM; ++c) { float x = v1s[c][r]; ss += x * x; }
            float inv = 1.0f / (EPSN + sqrtf(ss));
            s1t[r] = ss * inv * inv;
            r1t[r] = inv;
        } else {
            #pragma unroll
            for (int c = 0; c < CDIM; ++c) { float x = v2s[c][r]; ss += x * x; }
            float inv = 1.0f / (EPSN + sqrtf(ss));
            s2t[r] = ss * inv * inv;
            r2t[r] = inv;
        }
    }
    __syncthreads();

    // ---- main: each thread computes a 4x4 pair sub-tile
    const int tx = t & 15;     // j group
    const int ty = t >> 4;     // i group
    const int jb = tx * 4;
    const int ib = ty * 4;

    float acc0[4][4] = {{0}};  // W0-weighted dot
    float acc1[4][4] = {{0}};  // W1-weighted dot
    float accd[4][4] = {{0}};  // plain dot

    #pragma unroll 4
    for (int c = 0; c < CDIM; ++c) {
        f4 a   = *(const f4*)&v1s[c][ib];
        f4 b   = *(const f4*)&v2s[c][jb];
        f4 bw0 = *(const f4*)&v2w0[c][jb];
        f4 bw1 = *(const f4*)&v2w1[c][jb];
        #pragma unroll
        for (int ii = 0; ii < 4; ++ii) {
            #pragma unroll
            for (int jj = 0; jj < 4; ++jj) {
                acc0[ii][jj] += a[ii] * bw0[jj];
                acc1[ii][jj] += a[ii] * bw1[jj];
                accd[ii][jj] += a[ii] * b[jj];
            }
        }
    }

    const float b0 = bias[0];
    const float b1 = bias[1];

    #pragma unroll
    for (int ii = 0; ii < 4; ++ii) {
        const int i  = i0 + ib + ii;
        const float s1 = s1t[ib + ii];
        const float r1 = r1t[ib + ii];

        f4 o01, o23, dn;
        o01[0] = acc0[ii][0] + b0;  o01[1] = acc1[ii][0] + b1;
        o01[2] = acc0[ii][1] + b0;  o01[3] = acc1[ii][1] + b1;
        o23[0] = acc0[ii][2] + b0;  o23[1] = acc1[ii][2] + b1;
        o23[2] = acc0[ii][3] + b0;  o23[3] = acc1[ii][3] + b1;

        #pragma unroll
        for (int jj = 0; jj < 4; ++jj) {
            float d2 = s1 + s2t[jb + jj]
                     - 2.0f * accd[ii][jj] * r1 * r2t[jb + jj];
            dn[jj] = sqrtf(fmaxf(d2, 0.0f));
        }

        const size_t pair0 = (size_t)i * N + (j0 + jb);
        *(f4*)&out[pair0 * 2]     = o01;
        *(f4*)&out[pair0 * 2 + 4] = o23;
        *(f4*)&onorm[pair0]       = dn;
    }
}

extern "C" void kernel_launch(void* const* d_in, const int* in_sizes, int n_in,
                              void* d_out, int out_size, void* d_ws, size_t ws_size,
                              hipStream_t stream) {
    const float* g1   = (const float*)d_in[0];
    const float* g2   = (const float*)d_in[1];
    const float* W    = (const float*)d_in[2];
    const float* bias = (const float*)d_in[3];

    const int N = in_sizes[0] / CDIM;          // 1024 voxels
    float* out   = (float*)d_out;              // [N*N, 2]
    float* onorm = out + (size_t)2 * N * N;    // [N, N]

    dim3 grid(N / TILE, N / TILE);             // 16 x 16 blocks
    descmatch_kernel<<<grid, 256, 0, stream>>>(g1, g2, W, bias, out, onorm, N);
}